// Round 9
// baseline (250.235 us; speedup 1.0000x reference)
//
#include <hip/hip_runtime.h>

typedef float f2 __attribute__((ext_vector_type(2)));

#define IMG 512
#define TW 32
#define TH 32
#define NG 12            // float4 col-groups per tile row: 48 cols = 32 out + 8 halo each side
#define RS 102           // unified plane row stride in f2 (816 B; 204 dwords, odd*4 -> good banks)
#define BOFF 48          // B-part offset within a row, in f2 (384 B, 16B-aligned)
#define N_TOT (16 * 3 * 512 * 512)
#define NBLK (256 * 48)  // total blocks of ssim_main
#define NSLOT 1024       // fallback atomic slots

// Gaussian(win=11, sigma=1.5), normalized, pre-doubled (SGPR-pair broadcast for pk ops).
__device__ __constant__ f2 Gw2[11] = {
    {0.00102838f, 0.00102838f}, {0.00759876f, 0.00759876f},
    {0.03600077f, 0.03600077f}, {0.10936086f, 0.10936086f},
    {0.21300537f, 0.21300537f}, {0.26601173f, 0.26601173f},
    {0.21300537f, 0.21300537f}, {0.10936086f, 0.10936086f},
    {0.03600077f, 0.03600077f}, {0.00759876f, 0.00759876f},
    {0.00102838f, 0.00102838f}};

// Packed vertical taps for a row-pair from one input row k.
__device__ __forceinline__ void vtaps(const float4 P, const float4 T, const int k,
                                      f2 A0[4][2], f2 A1[4][2]) {
    const f2 p[2] = {{P.x, P.y}, {P.z, P.w}};
    const f2 t[2] = {{T.x, T.y}, {T.z, T.w}};
#pragma unroll
    for (int h = 0; h < 2; ++h) {
        const f2 ss = p[h] * p[h] + t[h] * t[h];
        const f2 pt = p[h] * t[h];
        if (k < 11) {                              // tap k for row r0
            const f2 w = Gw2[k];
            A0[0][h] += w * p[h];
            A0[1][h] += w * t[h];
            A0[2][h] += w * ss;
            A0[3][h] += w * pt;
        }
        if (k > 0) {                               // tap k-1 for row r0+1
            const f2 w = Gw2[k - 1];
            A1[0][h] += w * p[h];
            A1[1][h] += w * t[h];
            A1[2][h] += w * ss;
            A1[3][h] += w * pt;
        }
    }
}

// LDS = 26128 B -> 26624 allocated -> 6 blocks/CU = 24 waves/CU (6 waves/SIMD).
// launch_bounds(256,6) caps VGPR at 84 (>= the 60 this kernel needs; no spill).
// NOTE (round-8 lesson): do NOT hand-pipeline the k-loop — explicit load rotation
// across the vtaps call caused scratch spill (WRITE_SIZE 384 B -> 89.6 MB, 79->126 us).
__global__ __launch_bounds__(256, 6) void ssim_main(const float* __restrict__ pred,
                                                    const float* __restrict__ tgt,
                                                    float* __restrict__ ws,
                                                    int parts_mode) {
    // Unified vertically-blurred plane, 32 rows x (48 A-cols | 48 B-cols), stride 102 f2.
    //   A(row,c) = (vblur p, vblur t)          at plane[row*RS + c]
    //   B(row,c) = (vblur p^2+t^2, vblur p*t)  at plane[row*RS + BOFF + c]
    __shared__ __align__(16) f2 plane[TH * RS];   // 26112 B
    __shared__ float red[4];

    const int tid = threadIdx.x;
    const int tile = blockIdx.x;             // 16x16 tiles of 32x32
    const int plane_id = blockIdx.y;         // 48 planes
    const int tile_x = tile & 15;
    const int tile_y = tile >> 4;
    const int tx = tile_x * TW;
    const int ty = tile_y * TH;
    const float* pbase = pred + (size_t)plane_id * (IMG * IMG);
    const float* tbase = tgt + (size_t)plane_id * (IMG * IMG);

    // ---- Phase 1: vertical 11-tap blur straight from global, row-pair per task ----
    if (tid < NG * 16) {
        const int g4 = tid % NG;             // col group
        const int rp = tid / NG;             // row pair
        const int r0 = rp * 2;               // local output row
        const int col = tx - 8 + (g4 << 2);  // global col of float4 (16B-aligned)
        const int ybase = ty + r0 - 5;

        f2 A0[4][2], A1[4][2];
#pragma unroll
        for (int q = 0; q < 4; ++q)
#pragma unroll
            for (int h = 0; h < 2; ++h) { A0[q][h] = (f2)0.f; A1[q][h] = (f2)0.f; }

        // Block-uniform branch (scalar, no divergence); loads plain, compiler-scheduled.
        if ((unsigned)(tile_x - 1) < 14u && (unsigned)(tile_y - 1) < 14u) {
            const float* pp = pbase + (ybase * IMG + col);
            const float* tp = tbase + (ybase * IMG + col);
#pragma unroll
            for (int k = 0; k < 12; ++k) {
                const float4 P = *(const float4*)(pp + k * IMG);
                const float4 T = *(const float4*)(tp + k * IMG);
                vtaps(P, T, k, A0, A1);
            }
        } else {
            const bool xin = (unsigned)col < (unsigned)IMG;  // all-in or all-out
#pragma unroll
            for (int k = 0; k < 12; ++k) {
                const int y = ybase + k;
                float4 P = make_float4(0.f, 0.f, 0.f, 0.f);
                float4 T = make_float4(0.f, 0.f, 0.f, 0.f);
                if (xin && (unsigned)y < (unsigned)IMG) {
                    const int gidx = y * IMG + col;
                    P = *(const float4*)(pbase + gidx);
                    T = *(const float4*)(tbase + gidx);
                }
                vtaps(P, T, k, A0, A1);
            }
        }

        // Transpose in registers -> interleaved b128 stores (A and B parts of the row).
        const int cb = g4 << 2;              // col base (col 0 == global tx-8)
#pragma unroll
        for (int r = 0; r < 2; ++r) {
            f2 (*A)[2] = r ? A1 : A0;
            f2* rowA = &plane[(r0 + r) * RS + cb];
            f2* rowB = rowA + BOFF;
            *(float4*)rowA       = make_float4(A[0][0].x, A[1][0].x, A[0][0].y, A[1][0].y);
            *(float4*)(rowA + 2) = make_float4(A[0][1].x, A[1][1].x, A[0][1].y, A[1][1].y);
            *(float4*)rowB       = make_float4(A[2][0].x, A[3][0].x, A[2][0].y, A[3][0].y);
            *(float4*)(rowB + 2) = make_float4(A[2][1].x, A[3][1].x, A[2][1].y, A[3][1].y);
        }
    }
    __syncthreads();

    // ---- Phase 2: packed horizontal 11-tap blur + SSIM map, 4 outputs per thread ----
    float lsum = 0.f;
    {
        const int oy = tid >> 3;             // 32 rows
        const int ox = (tid & 7) << 2;       // 8 groups of 4 output cols
        // output local col X needs plane cols X+3 .. X+13; union j=0..3: ox+3..ox+16.
        // Load cols ox+2 .. ox+17 (16 f2, 16B-aligned).

        f2 acc[4];                           // (mu1, mu2) per j
#pragma unroll
        for (int j = 0; j < 4; ++j) acc[j] = (f2)0.f;
        {
            const float4* rowA = (const float4*)&plane[oy * RS + ox + 2];
            f2 w[16];
#pragma unroll
            for (int i = 0; i < 8; ++i) {
                const float4 q = rowA[i];
                w[2 * i] = (f2){q.x, q.y};
                w[2 * i + 1] = (f2){q.z, q.w};
            }
#pragma unroll
            for (int k = 0; k < 11; ++k) {
                const f2 g = Gw2[k];
#pragma unroll
                for (int j = 0; j < 4; ++j) acc[j] += g * w[1 + j + k];
            }
        }
        f2 sacc[4];                          // (bss, bpt) per j
#pragma unroll
        for (int j = 0; j < 4; ++j) sacc[j] = (f2)0.f;
        {
            const float4* rowB = (const float4*)&plane[oy * RS + BOFF + ox + 2];
            f2 w[16];
#pragma unroll
            for (int i = 0; i < 8; ++i) {
                const float4 q = rowB[i];
                w[2 * i] = (f2){q.x, q.y};
                w[2 * i + 1] = (f2){q.z, q.w};
            }
#pragma unroll
            for (int k = 0; k < 11; ++k) {
                const f2 g = Gw2[k];
#pragma unroll
                for (int j = 0; j < 4; ++j) sacc[j] += g * w[1 + j + k];
            }
        }

        const float C1 = 0.0001f;            // 0.01^2
        const float C2 = 0.0009f;            // 0.03^2
#pragma unroll
        for (int j = 0; j < 4; ++j) {
            const float m1 = acc[j].x, m2 = acc[j].y;
            const float bss = sacc[j].x, bpt = sacc[j].y;
            const float mu1s = m1 * m1;
            const float mu2s = m2 * m2;
            const float mu12 = m1 * m2;
            const float A = mu1s + mu2s;
            const float s12 = bpt - mu12;    // sigma12
            const float sden = bss - A;      // sigma1^2 + sigma2^2
            const float num = fmaf(2.f, mu12, C1) * fmaf(2.f, s12, C2);
            const float den = (A + C1) * (sden + C2);
            lsum += num * __builtin_amdgcn_rcpf(den);   // rcp err ~1e-7 << 1.98e-2 threshold
        }
    }

    // ---- Reduction: wave shuffle -> LDS -> one plain store per block ----
#pragma unroll
    for (int off = 32; off > 0; off >>= 1) lsum += __shfl_down(lsum, off, 64);
    if ((tid & 63) == 0) red[tid >> 6] = lsum;
    __syncthreads();
    if (tid == 0) {
        const float bs = (red[0] + red[1]) + (red[2] + red[3]);
        const int bid = blockIdx.y * gridDim.x + blockIdx.x;
        if (parts_mode) {
            ws[bid] = bs;                    // contention-free
        } else {
            atomicAdd(&ws[bid & (NSLOT - 1)], bs);  // fallback: shallow contention
        }
    }
}

// Sum `count4` float4 partials from ws, write 1 - sum/N.
__global__ __launch_bounds__(1024) void ssim_final(const float4* __restrict__ ws4,
                                                   float* __restrict__ out, int count4) {
    __shared__ float red[16];
    const int tid = threadIdx.x;
    float s = 0.f;
    for (int i = tid; i < count4; i += 1024) {
        const float4 w = ws4[i];
        s += (w.x + w.y) + (w.z + w.w);
    }
#pragma unroll
    for (int off = 32; off > 0; off >>= 1) s += __shfl_down(s, off, 64);
    if ((tid & 63) == 0) red[tid >> 6] = s;
    __syncthreads();
    if (tid == 0) {
        float tot = 0.f;
#pragma unroll
        for (int i = 0; i < 16; ++i) tot += red[i];
        out[0] = 1.0f - tot * (1.0f / (float)N_TOT);
    }
}

extern "C" void kernel_launch(void* const* d_in, const int* in_sizes, int n_in,
                              void* d_out, int out_size, void* d_ws, size_t ws_size,
                              hipStream_t stream) {
    const float* pred = (const float*)d_in[0];
    const float* tgt = (const float*)d_in[1];
    float* out = (float*)d_out;
    float* ws = (float*)d_ws;

    const int parts_mode = (ws_size >= (size_t)NBLK * sizeof(float)) ? 1 : 0;
    if (!parts_mode) {
        hipMemsetAsync(ws, 0, NSLOT * sizeof(float), stream);
    }
    dim3 grid(256, 48);  // 16x16 tiles x (16*3) planes
    ssim_main<<<grid, 256, 0, stream>>>(pred, tgt, ws, parts_mode);
    ssim_final<<<1, 1024, 0, stream>>>((const float4*)ws, out,
                                       (parts_mode ? NBLK : NSLOT) / 4);
}

// Round 10
// 164.750 us; speedup vs baseline: 1.5189x; 1.5189x over previous
//
#include <hip/hip_runtime.h>

typedef float f2 __attribute__((ext_vector_type(2)));

#define IMG 512
#define TW 32
#define TH 32
#define NG 12            // float4 col-groups per tile row: 48 cols = 32 out + 8 halo each side
#define RS 102           // unified plane row stride in f2 (816 B; LDS 26624 alloc -> 6 blocks/CU)
#define BOFF 48          // B-part offset within a row, in f2 (384 B, 16B-aligned)
#define N_TOT (16 * 3 * 512 * 512)
#define NBLK (256 * 48)  // total blocks of ssim_main
#define NSLOT 1024       // fallback atomic slots

// Gaussian(win=11, sigma=1.5), normalized, pre-doubled (SGPR-pair broadcast for pk ops).
__device__ __constant__ f2 Gw2[11] = {
    {0.00102838f, 0.00102838f}, {0.00759876f, 0.00759876f},
    {0.03600077f, 0.03600077f}, {0.10936086f, 0.10936086f},
    {0.21300537f, 0.21300537f}, {0.26601173f, 0.26601173f},
    {0.21300537f, 0.21300537f}, {0.10936086f, 0.10936086f},
    {0.03600077f, 0.03600077f}, {0.00759876f, 0.00759876f},
    {0.00102838f, 0.00102838f}};

// Packed vertical taps for a row-pair from one input row k.
__device__ __forceinline__ void vtaps(const float4 P, const float4 T, const int k,
                                      f2 A0[4][2], f2 A1[4][2]) {
    const f2 p[2] = {{P.x, P.y}, {P.z, P.w}};
    const f2 t[2] = {{T.x, T.y}, {T.z, T.w}};
#pragma unroll
    for (int h = 0; h < 2; ++h) {
        const f2 ss = p[h] * p[h] + t[h] * t[h];
        const f2 pt = p[h] * t[h];
        if (k < 11) {                              // tap k for row r0
            const f2 w = Gw2[k];
            A0[0][h] += w * p[h];
            A0[1][h] += w * t[h];
            A0[2][h] += w * ss;
            A0[3][h] += w * pt;
        }
        if (k > 0) {                               // tap k-1 for row r0+1
            const f2 w = Gw2[k - 1];
            A1[0][h] += w * p[h];
            A1[1][h] += w * t[h];
            A1[2][h] += w * ss;
            A1[3][h] += w * pt;
        }
    }
}

// PINNED at (256,8): measured three times VGPR=60/no-spill; (256,5) and (256,6)
// both triggered pathological spill (WRITE_SIZE 89-112 MB, VGPR 40-48). Do not touch.
// Also: never hand-pipeline the k-loop (round-8 spill); plain loads, compiler schedules.
__global__ __launch_bounds__(256, 8) void ssim_main(const float* __restrict__ pred,
                                                    const float* __restrict__ tgt,
                                                    float* __restrict__ ws,
                                                    int parts_mode) {
    // Unified vertically-blurred plane, 32 rows x (48 A-cols | 48 B-cols), stride 102 f2.
    //   A(row,c) = (vblur p, vblur t)          at plane[row*RS + c]
    //   B(row,c) = (vblur p^2+t^2, vblur p*t)  at plane[row*RS + BOFF + c]
    // Row stride 204 dwords: bank-quad shift per row = 3*oy mod 8 (full permutation).
    __shared__ __align__(16) f2 plane[TH * RS];   // 26112 B -> 26624 alloc -> 6 blocks/CU
    __shared__ float red[4];

    const int tid = threadIdx.x;
    const int tile = blockIdx.x;             // 16x16 tiles of 32x32
    const int plane_id = blockIdx.y;         // 48 planes
    const int tile_x = tile & 15;
    const int tile_y = tile >> 4;
    const int tx = tile_x * TW;
    const int ty = tile_y * TH;
    const float* pbase = pred + (size_t)plane_id * (IMG * IMG);
    const float* tbase = tgt + (size_t)plane_id * (IMG * IMG);

    // ---- Phase 1: vertical 11-tap blur straight from global, row-pair per task ----
    if (tid < NG * 16) {
        const int g4 = tid % NG;             // col group
        const int rp = tid / NG;             // row pair
        const int r0 = rp * 2;               // local output row
        const int col = tx - 8 + (g4 << 2);  // global col of float4 (16B-aligned)
        const int ybase = ty + r0 - 5;

        f2 A0[4][2], A1[4][2];
#pragma unroll
        for (int q = 0; q < 4; ++q)
#pragma unroll
            for (int h = 0; h < 2; ++h) { A0[q][h] = (f2)0.f; A1[q][h] = (f2)0.f; }

        // Block-uniform branch (scalar, no divergence); loads plain, compiler-scheduled.
        if ((unsigned)(tile_x - 1) < 14u && (unsigned)(tile_y - 1) < 14u) {
            const float* pp = pbase + (ybase * IMG + col);
            const float* tp = tbase + (ybase * IMG + col);
#pragma unroll
            for (int k = 0; k < 12; ++k) {
                const float4 P = *(const float4*)(pp + k * IMG);
                const float4 T = *(const float4*)(tp + k * IMG);
                vtaps(P, T, k, A0, A1);
            }
        } else {
            const bool xin = (unsigned)col < (unsigned)IMG;  // all-in or all-out
#pragma unroll
            for (int k = 0; k < 12; ++k) {
                const int y = ybase + k;
                float4 P = make_float4(0.f, 0.f, 0.f, 0.f);
                float4 T = make_float4(0.f, 0.f, 0.f, 0.f);
                if (xin && (unsigned)y < (unsigned)IMG) {
                    const int gidx = y * IMG + col;
                    P = *(const float4*)(pbase + gidx);
                    T = *(const float4*)(tbase + gidx);
                }
                vtaps(P, T, k, A0, A1);
            }
        }

        // Transpose in registers -> interleaved b128 stores (A and B parts of the row).
        const int cb = g4 << 2;              // col base (col 0 == global tx-8)
#pragma unroll
        for (int r = 0; r < 2; ++r) {
            f2 (*A)[2] = r ? A1 : A0;
            f2* rowA = &plane[(r0 + r) * RS + cb];
            f2* rowB = rowA + BOFF;
            *(float4*)rowA       = make_float4(A[0][0].x, A[1][0].x, A[0][0].y, A[1][0].y);
            *(float4*)(rowA + 2) = make_float4(A[0][1].x, A[1][1].x, A[0][1].y, A[1][1].y);
            *(float4*)rowB       = make_float4(A[2][0].x, A[3][0].x, A[2][0].y, A[3][0].y);
            *(float4*)(rowB + 2) = make_float4(A[2][1].x, A[3][1].x, A[2][1].y, A[3][1].y);
        }
    }
    __syncthreads();

    // ---- Phase 2: packed horizontal 11-tap blur + SSIM map, 4 outputs per thread ----
    float lsum = 0.f;
    {
        const int oy = tid >> 3;             // 32 rows
        const int ox = (tid & 7) << 2;       // 8 groups of 4 output cols
        // output local col X needs plane cols X+3 .. X+13; union j=0..3: ox+3..ox+16.
        // Load cols ox+2 .. ox+17 (16 f2, 16B-aligned).

        f2 acc[4];                           // (mu1, mu2) per j
#pragma unroll
        for (int j = 0; j < 4; ++j) acc[j] = (f2)0.f;
        {
            const float4* rowA = (const float4*)&plane[oy * RS + ox + 2];
            f2 w[16];
#pragma unroll
            for (int i = 0; i < 8; ++i) {
                const float4 q = rowA[i];
                w[2 * i] = (f2){q.x, q.y};
                w[2 * i + 1] = (f2){q.z, q.w};
            }
#pragma unroll
            for (int k = 0; k < 11; ++k) {
                const f2 g = Gw2[k];
#pragma unroll
                for (int j = 0; j < 4; ++j) acc[j] += g * w[1 + j + k];
            }
        }
        f2 sacc[4];                          // (bss, bpt) per j
#pragma unroll
        for (int j = 0; j < 4; ++j) sacc[j] = (f2)0.f;
        {
            const float4* rowB = (const float4*)&plane[oy * RS + BOFF + ox + 2];
            f2 w[16];
#pragma unroll
            for (int i = 0; i < 8; ++i) {
                const float4 q = rowB[i];
                w[2 * i] = (f2){q.x, q.y};
                w[2 * i + 1] = (f2){q.z, q.w};
            }
#pragma unroll
            for (int k = 0; k < 11; ++k) {
                const f2 g = Gw2[k];
#pragma unroll
                for (int j = 0; j < 4; ++j) sacc[j] += g * w[1 + j + k];
            }
        }

        const float C1 = 0.0001f;            // 0.01^2
        const float C2 = 0.0009f;            // 0.03^2
#pragma unroll
        for (int j = 0; j < 4; ++j) {
            const float m1 = acc[j].x, m2 = acc[j].y;
            const float bss = sacc[j].x, bpt = sacc[j].y;
            const float mu1s = m1 * m1;
            const float mu2s = m2 * m2;
            const float mu12 = m1 * m2;
            const float A = mu1s + mu2s;
            const float s12 = bpt - mu12;    // sigma12
            const float sden = bss - A;      // sigma1^2 + sigma2^2
            const float num = fmaf(2.f, mu12, C1) * fmaf(2.f, s12, C2);
            const float den = (A + C1) * (sden + C2);
            lsum += num * __builtin_amdgcn_rcpf(den);   // rcp err ~1e-7 << 1.98e-2 threshold
        }
    }

    // ---- Reduction: wave shuffle -> LDS -> one plain store per block ----
#pragma unroll
    for (int off = 32; off > 0; off >>= 1) lsum += __shfl_down(lsum, off, 64);
    if ((tid & 63) == 0) red[tid >> 6] = lsum;
    __syncthreads();
    if (tid == 0) {
        const float bs = (red[0] + red[1]) + (red[2] + red[3]);
        const int bid = blockIdx.y * gridDim.x + blockIdx.x;
        if (parts_mode) {
            ws[bid] = bs;                    // contention-free
        } else {
            atomicAdd(&ws[bid & (NSLOT - 1)], bs);  // fallback: shallow contention
        }
    }
}

// Sum `count4` float4 partials from ws, write 1 - sum/N.
__global__ __launch_bounds__(1024) void ssim_final(const float4* __restrict__ ws4,
                                                   float* __restrict__ out, int count4) {
    __shared__ float red[16];
    const int tid = threadIdx.x;
    float s = 0.f;
    for (int i = tid; i < count4; i += 1024) {
        const float4 w = ws4[i];
        s += (w.x + w.y) + (w.z + w.w);
    }
#pragma unroll
    for (int off = 32; off > 0; off >>= 1) s += __shfl_down(s, off, 64);
    if ((tid & 63) == 0) red[tid >> 6] = s;
    __syncthreads();
    if (tid == 0) {
        float tot = 0.f;
#pragma unroll
        for (int i = 0; i < 16; ++i) tot += red[i];
        out[0] = 1.0f - tot * (1.0f / (float)N_TOT);
    }
}

extern "C" void kernel_launch(void* const* d_in, const int* in_sizes, int n_in,
                              void* d_out, int out_size, void* d_ws, size_t ws_size,
                              hipStream_t stream) {
    const float* pred = (const float*)d_in[0];
    const float* tgt = (const float*)d_in[1];
    float* out = (float*)d_out;
    float* ws = (float*)d_ws;

    const int parts_mode = (ws_size >= (size_t)NBLK * sizeof(float)) ? 1 : 0;
    if (!parts_mode) {
        hipMemsetAsync(ws, 0, NSLOT * sizeof(float), stream);
    }
    dim3 grid(256, 48);  // 16x16 tiles x (16*3) planes
    ssim_main<<<grid, 256, 0, stream>>>(pred, tgt, ws, parts_mode);
    ssim_final<<<1, 1024, 0, stream>>>((const float4*)ws, out,
                                       (parts_mode ? NBLK : NSLOT) / 4);
}